// Round 2
// baseline (88.186 us; speedup 1.0000x reference)
//
#include <hip/hip_runtime.h>
#include <hip/hip_bf16.h>

// Problem: B=4, N=512, D=1024, H=256. Inputs fp32, OUTPUT fp32.
//   o[b,n,h]     = sum_d x[b,n,d]*W1[h,d] + b1[h]                  (2048x256, K=1024)
//   out[b,i,j,c] = sum_h (o[b,i,h]*W2[c,h]) * o[b,j,h] + b2[c]     (per b,c: 512x512, K=256)
//
// R12: collapse stage-1 to ONE kernel (no split-K, no P round-trip, no s1_reduce).
//   Evidence: top-5 rocprof dispatches are all 256 MiB ws poison-fills (~43 us,
//   78% HBM peak); our kernels are each <42 us and R11's stage2 occupancy fix was
//   noise -> pipeline length (launches + P round-trip), not per-kernel compute,
//   is the remaining lever.
//   s1_fused: 256 blocks = (mT 0..127 x hT 0..1). Block computes o[mT*16..+15][hT*128..+127]
//   with full K=1024 fp32 MFMA accumulation (more accurate than old bf16 partials),
//   then writes o, u0 = bf16(o*W2[0]), u1 = bf16(o*W2[1]) directly.
//   stage2: unchanged R11 (64x64 supertile, 8 waves, 16x32 per wave).

typedef __attribute__((ext_vector_type(8))) short bf16x8;   // 8 bf16 = 4 VGPRs
typedef __attribute__((ext_vector_type(4))) short bf16x4;   // 4 bf16 = 2 VGPRs
typedef __attribute__((ext_vector_type(4))) float f32x4;
typedef __attribute__((ext_vector_type(2))) float f32x2;

__device__ __forceinline__ unsigned short f2bf(float f) {
    __hip_bfloat16 h = __float2bfloat16(f);   // RNE
    unsigned short s;
    __builtin_memcpy(&s, &h, 2);
    return s;
}

__device__ __forceinline__ float bf2f(unsigned short b) {
    unsigned int u = ((unsigned int)b) << 16;
    float f;
    __builtin_memcpy(&f, &u, 4);
    return f;
}

__device__ __forceinline__ bf16x4 cvt4(f32x4 v) {
    bf16x4 r;
    r[0] = (short)f2bf(v[0]); r[1] = (short)f2bf(v[1]);
    r[2] = (short)f2bf(v[2]); r[3] = (short)f2bf(v[3]);
    return r;
}

// ---------------- Stage 1 fused: o/u0/u1 in one pass, full-K fp32 accumulation ----------
#define S1_LD 72

__global__ __launch_bounds__(256) void s1_fused(
    const float* __restrict__ x,        // [2048][1024]
    const float* __restrict__ W1,       // [256][1024]
    const float* __restrict__ b1,       // [256]
    const float* __restrict__ W2,       // [2][256]
    unsigned short* __restrict__ o,     // [2048][256] bf16
    unsigned short* __restrict__ u0,    // [2048][256] bf16
    unsigned short* __restrict__ u1)    // [2048][256] bf16
{
    __shared__ unsigned short xs[16 * S1_LD];     // 2304 B
    __shared__ unsigned short ws_[128 * S1_LD];   // 18432 B
    const int tid  = threadIdx.x;
    const int lane = tid & 63;
    const int wave = tid >> 6;          // 0..3 -> 32-h band within the 128-h strip
    const int mT = blockIdx.x >> 1;     // 0..127 -> rows mT*16 .. +15
    const int hT = blockIdx.x & 1;      // 0..1   -> h-cols hT*128 .. +127
    const int l15 = lane & 15;
    const int quad = lane >> 4;

    f32x4 acc[2];
    acc[0] = (f32x4){0.f, 0.f, 0.f, 0.f};
    acc[1] = (f32x4){0.f, 0.f, 0.f, 0.f};

    for (int ph = 0; ph < 16; ++ph) {            // 16 x 64-wide K phases
        const int k0 = ph * 64;
        if (ph) __syncthreads();

        {   // x tile: 16x64 fp32 -> bf16 LDS (1 f32x4 per thread)
            const int row = tid >> 4;
            const int c4  = tid & 15;
            f32x4 v = *(const f32x4*)(x + (mT * 16 + row) * 1024 + k0 + c4 * 4);
            *(bf16x4*)(&xs[row * S1_LD + c4 * 4]) = cvt4(v);
        }
        #pragma unroll
        for (int i = 0; i < 8; ++i) {            // W1 tile: 128x64 (8 f32x4 per thread)
            const int idx = i * 256 + tid;
            const int row = idx >> 4;
            const int c4  = idx & 15;
            f32x4 v = *(const f32x4*)(W1 + (hT * 128 + row) * 1024 + k0 + c4 * 4);
            *(bf16x4*)(&ws_[row * S1_LD + c4 * 4]) = cvt4(v);
        }
        __syncthreads();

        #pragma unroll
        for (int s = 0; s < 2; ++s) {
            bf16x8 a = *(const bf16x8*)(&xs[l15 * S1_LD + s * 32 + quad * 8]);
            #pragma unroll
            for (int g = 0; g < 2; ++g) {
                bf16x8 bfr = *(const bf16x8*)(&ws_[(wave * 32 + g * 16 + l15) * S1_LD + s * 32 + quad * 8]);
                acc[g] = __builtin_amdgcn_mfma_f32_16x16x32_bf16(a, bfr, acc[g], 0, 0, 0);
            }
        }
    }

    // Epilogue: o = bf16(acc + b1); u_c = bf16(bf2f(o) * W2[c]) — same rounding
    // path for stage2 operands as before (u built from the ROUNDED o).
    #pragma unroll
    for (int g = 0; g < 2; ++g) {
        const int h = hT * 128 + wave * 32 + g * 16 + l15;
        const float bb  = b1[h];
        const float w20 = W2[h];
        const float w21 = W2[256 + h];
        #pragma unroll
        for (int r = 0; r < 4; ++r) {
            const int m = mT * 16 + quad * 4 + r;
            const unsigned short ob = f2bf(acc[g][r] + bb);
            const float of = bf2f(ob);
            o [m * 256 + h] = ob;
            u0[m * 256 + h] = f2bf(of * w20);
            u1[m * 256 + h] = f2bf(of * w21);
        }
    }
}

// ---------------- Stage 2 (R11, unchanged): 64x64 supertile, 8 waves ----------------
#define S2_LD 264   // shorts per LDS row (256 + 8 pad); 64*264*2 = 33792 B

__global__ __launch_bounds__(512) void stage2_kernel(
    const unsigned short* __restrict__ o,    // [4][512][256] bf16
    const unsigned short* __restrict__ u0,   // [4][512][256] bf16
    const unsigned short* __restrict__ u1,   // [4][512][256] bf16
    const float* __restrict__ b2,            // [2] fp32
    float* __restrict__ out)                 // [4][512][512][2] fp32
{
    __shared__ unsigned short js[64 * S2_LD];
    const int tid  = threadIdx.x;
    const int lane = tid & 63;
    const int wave = tid >> 6;          // 0..7
    const int blk  = blockIdx.x;        // 0..255
    const int b  = blk >> 6;            // 4
    const int iS = (blk >> 3) & 7;      // 8
    const int jS = blk & 7;             // 8
    const int l15 = lane & 15;
    const int quad = lane >> 4;
    const int wi = wave & 3;            // i 16-band within the 64-row supertile
    const int wj = wave >> 2;           // j 32-half within the 64-col supertile

    // Stage j-rows o[b][jS*64 .. +63][0:256] into LDS (coalesced 16B copies).
    const unsigned short* jbase = o + (b * 512 + jS * 64) * 256;
    #pragma unroll
    for (int i = 0; i < 4; ++i) {
        const int idx = i * 512 + tid;      // 0..2047 = 64 rows x 32 chunks
        const int row = idx >> 5;
        const int c8  = idx & 31;
        *(bf16x8*)(&js[row * S2_LD + c8 * 8]) = *(const bf16x8*)(jbase + row * 256 + c8 * 8);
    }
    __syncthreads();

    const int ioff = ((b * 512 + iS * 64 + wi * 16 + l15) * 256) + quad * 8;
    const unsigned short* irow0 = u0 + ioff;
    const unsigned short* irow1 = u1 + ioff;

    f32x4 acc0[2], acc1[2];
    #pragma unroll
    for (int g = 0; g < 2; ++g) {
        acc0[g] = (f32x4){0.f, 0.f, 0.f, 0.f};
        acc1[g] = (f32x4){0.f, 0.f, 0.f, 0.f};
    }

    #pragma unroll
    for (int s = 0; s < 8; ++s) {
        const int k = s * 32;
        bf16x8 a0 = *(const bf16x8*)(irow0 + k);
        bf16x8 a1 = *(const bf16x8*)(irow1 + k);
        #pragma unroll
        for (int g = 0; g < 2; ++g) {
            bf16x8 bj = *(const bf16x8*)(&js[(wj * 32 + g * 16 + l15) * S2_LD + k + quad * 8]);
            acc0[g] = __builtin_amdgcn_mfma_f32_16x16x32_bf16(a0, bj, acc0[g], 0, 0, 0);
            acc1[g] = __builtin_amdgcn_mfma_f32_16x16x32_bf16(a1, bj, acc1[g], 0, 0, 0);
        }
    }

    const float bias0 = b2[0];
    const float bias1 = b2[1];
    #pragma unroll
    for (int g = 0; g < 2; ++g) {
        const int j = jS * 64 + wj * 32 + g * 16 + l15;      // n-index = lane&15
        #pragma unroll
        for (int r = 0; r < 4; ++r) {
            const int i = iS * 64 + wi * 16 + quad * 4 + r;  // m-index
            f32x2 v;
            v[0] = acc0[g][r] + bias0;
            v[1] = acc1[g][r] + bias1;
            *(f32x2*)(out + (((b * 512 + i) * 512) + j) * 2) = v;
        }
    }
}

extern "C" void kernel_launch(void* const* d_in, const int* in_sizes, int n_in,
                              void* d_out, int out_size, void* d_ws, size_t ws_size,
                              hipStream_t stream) {
    const float* x  = (const float*)d_in[0];   // [4,512,1024] fp32
    const float* W1 = (const float*)d_in[1];   // [256,1024] fp32
    const float* b1 = (const float*)d_in[2];   // [256] fp32
    const float* W2 = (const float*)d_in[3];   // [2,256] fp32
    const float* b2 = (const float*)d_in[4];   // [2] fp32
    float* out = (float*)d_out;                // [4,512,512,2] fp32

    // ws layout:
    //   o  bf16 [2048][256] @ 0      (1 MB)
    //   u0 bf16 [2048][256] @ 1 MB   (1 MB)
    //   u1 bf16 [2048][256] @ 2 MB   (1 MB)
    unsigned short* o  = (unsigned short*)d_ws;
    unsigned short* u0 = (unsigned short*)((char*)d_ws + (1u << 20));
    unsigned short* u1 = (unsigned short*)((char*)d_ws + (2u << 20));

    s1_fused     <<<256, 256, 0, stream>>>(x, W1, b1, W2, o, u0, u1);
    stage2_kernel<<<256, 512, 0, stream>>>(o, u0, u1, b2, out);
}

// Round 3
// 85.676 us; speedup vs baseline: 1.0293x; 1.0293x over previous
//
#include <hip/hip_runtime.h>
#include <hip/hip_bf16.h>

// Problem: B=4, N=512, D=1024, H=256. Inputs fp32, OUTPUT fp32.
//   o[b,n,h]     = sum_d x[b,n,d]*W1[h,d] + b1[h]                  (2048x256, K=1024)
//   out[b,i,j,c] = sum_h (o[b,i,h]*W2[c,h]) * o[b,j,h] + b2[c]     (per b,c: 512x512, K=256)
//
// R13: revert R12 fusion (s1_fused was 1 wave/SIMD + 16 serial phases -> +6us).
//   Back to split-K s1_gemm + s1_reduce + stage2 (R11 = 81.9us), with s1_gemm
//   occupancy doubled: kT=16 (1024 blocks, ONE 64-wide K phase, single barrier),
//   LDS pad 72->68 shorts/row => 39.2 KB => 4 blocks/CU (launch_bounds(256,4)).
//   Bank check LD=68: frag-read banks (2*l15+4*quad)%32 -> ~2-way (free, m136);
//   old LD=72 was (4*(l15+quad))%32 -> 8-way.
//   s1_reduce: 16 partials, 512 blocks x 256 thr (4 elems/thread, 2 waves/SIMD).
//   stage2: unchanged R11 (64x64 supertile, 8 waves, 16x32 per wave).

typedef __attribute__((ext_vector_type(8))) short bf16x8;   // 8 bf16 = 4 VGPRs
typedef __attribute__((ext_vector_type(4))) short bf16x4;   // 4 bf16 = 2 VGPRs
typedef __attribute__((ext_vector_type(4))) float f32x4;
typedef __attribute__((ext_vector_type(2))) float f32x2;

__device__ __forceinline__ unsigned short f2bf(float f) {
    __hip_bfloat16 h = __float2bfloat16(f);   // RNE
    unsigned short s;
    __builtin_memcpy(&s, &h, 2);
    return s;
}

__device__ __forceinline__ float bf2f(unsigned short b) {
    unsigned int u = ((unsigned int)b) << 16;
    float f;
    __builtin_memcpy(&f, &u, 4);
    return f;
}

__device__ __forceinline__ bf16x4 cvt4(f32x4 v) {
    bf16x4 r;
    r[0] = (short)f2bf(v[0]); r[1] = (short)f2bf(v[1]);
    r[2] = (short)f2bf(v[2]); r[3] = (short)f2bf(v[3]);
    return r;
}

// ---------------- Stage 1a: split-K(16) GEMM -> bf16 partials ----------------
#define S1_LD 68    // shorts per LDS row (64 + 4 pad); 136 B row stride

__global__ __launch_bounds__(256, 4) void s1_gemm(
    const float* __restrict__ x,        // [2048][1024]
    const float* __restrict__ W1,       // [256][1024]
    unsigned short* __restrict__ P)     // [16][2048][256] bf16 partials
{
    __shared__ unsigned short xs[32 * S1_LD];    // 4352 B
    __shared__ unsigned short ws_[256 * S1_LD];  // 34816 B  (total 39168 B -> 4 blk/CU)
    const int tid  = threadIdx.x;
    const int lane = tid & 63;
    const int wave = tid >> 6;
    const int kT = blockIdx.x & 15;              // 0..15, K=64 each
    const int mT = blockIdx.x >> 4;              // 0..63, 32 rows each
    const int l15 = lane & 15;
    const int quad = lane >> 4;
    const int k0 = kT * 64;

    f32x4 acc[2][4];
    #pragma unroll
    for (int f = 0; f < 2; ++f)
        #pragma unroll
        for (int g = 0; g < 4; ++g)
            acc[f][g] = (f32x4){0.f, 0.f, 0.f, 0.f};

    #pragma unroll
    for (int i = 0; i < 2; ++i) {                // x tile: 32x64
        const int idx = i * 256 + tid;
        const int row = idx >> 4;
        const int c4  = idx & 15;
        f32x4 v = *(const f32x4*)(x + (mT * 32 + row) * 1024 + k0 + c4 * 4);
        *(bf16x4*)(&xs[row * S1_LD + c4 * 4]) = cvt4(v);
    }
    #pragma unroll 8
    for (int i = 0; i < 16; ++i) {               // W1 tile: 256x64
        const int idx = i * 256 + tid;
        const int row = idx >> 4;
        const int c4  = idx & 15;
        f32x4 v = *(const f32x4*)(W1 + row * 1024 + k0 + c4 * 4);
        *(bf16x4*)(&ws_[row * S1_LD + c4 * 4]) = cvt4(v);
    }
    __syncthreads();

    #pragma unroll
    for (int s = 0; s < 2; ++s) {
        bf16x8 a[2], b[4];
        #pragma unroll
        for (int f = 0; f < 2; ++f)
            a[f] = *(const bf16x8*)(&xs[(f * 16 + l15) * S1_LD + s * 32 + quad * 8]);
        #pragma unroll
        for (int g = 0; g < 4; ++g)
            b[g] = *(const bf16x8*)(&ws_[(wave * 64 + g * 16 + l15) * S1_LD + s * 32 + quad * 8]);
        #pragma unroll
        for (int f = 0; f < 2; ++f)
            #pragma unroll
            for (int g = 0; g < 4; ++g)
                acc[f][g] = __builtin_amdgcn_mfma_f32_16x16x32_bf16(a[f], b[g], acc[f][g], 0, 0, 0);
    }

    unsigned short* Pk = P + kT * (2048 * 256);
    #pragma unroll
    for (int f = 0; f < 2; ++f) {
        #pragma unroll
        for (int g = 0; g < 4; ++g) {
            const int h = wave * 64 + g * 16 + l15;
            #pragma unroll
            for (int r = 0; r < 4; ++r) {
                const int m = mT * 32 + f * 16 + quad * 4 + r;
                Pk[m * 256 + h] = f2bf(acc[f][g][r]);
            }
        }
    }
}

// ---------------- Stage 1b: o = bf16(sum_k P + b1); u_c = bf16(o * W2[c]) ----------------
// 512 blocks x 256 threads; each thread handles 4 consecutive h-elements.
__global__ __launch_bounds__(256) void s1_reduce(
    const unsigned short* __restrict__ P,  // [16][2048][256] bf16
    const float* __restrict__ b1,          // [256]
    const float* __restrict__ W2,          // [2][256]
    unsigned short* __restrict__ o,        // [2048][256] bf16
    unsigned short* __restrict__ u0,       // [2048][256] bf16
    unsigned short* __restrict__ u1)       // [2048][256] bf16
{
    const int base = (blockIdx.x * 256 + threadIdx.x) * 4;   // elem idx, 4 each
    const int h0 = base & 255;
    float s[4];
    {
        f32x4 bb = *(const f32x4*)(b1 + h0);
        #pragma unroll
        for (int j = 0; j < 4; ++j) s[j] = bb[j];
    }
    #pragma unroll
    for (int kt = 0; kt < 16; ++kt) {
        bf16x4 v = *(const bf16x4*)(P + kt * (2048 * 256) + base);
        #pragma unroll
        for (int j = 0; j < 4; ++j)
            s[j] += bf2f((unsigned short)v[j]);
    }
    f32x4 w0 = *(const f32x4*)(W2 + h0);
    f32x4 w1 = *(const f32x4*)(W2 + 256 + h0);
    bf16x4 ro, r0, r1;
    #pragma unroll
    for (int j = 0; j < 4; ++j) {
        const unsigned short ob = f2bf(s[j]);
        const float of = bf2f(ob);              // rounded o, matches stage2 operand path
        ro[j] = (short)ob;
        r0[j] = (short)f2bf(of * w0[j]);
        r1[j] = (short)f2bf(of * w1[j]);
    }
    *(bf16x4*)(o  + base) = ro;
    *(bf16x4*)(u0 + base) = r0;
    *(bf16x4*)(u1 + base) = r1;
}

// ---------------- Stage 2 (R11, unchanged): 64x64 supertile, 8 waves ----------------
#define S2_LD 264   // shorts per LDS row (256 + 8 pad); 64*264*2 = 33792 B

__global__ __launch_bounds__(512) void stage2_kernel(
    const unsigned short* __restrict__ o,    // [4][512][256] bf16
    const unsigned short* __restrict__ u0,   // [4][512][256] bf16
    const unsigned short* __restrict__ u1,   // [4][512][256] bf16
    const float* __restrict__ b2,            // [2] fp32
    float* __restrict__ out)                 // [4][512][512][2] fp32
{
    __shared__ unsigned short js[64 * S2_LD];
    const int tid  = threadIdx.x;
    const int lane = tid & 63;
    const int wave = tid >> 6;          // 0..7
    const int blk  = blockIdx.x;        // 0..255
    const int b  = blk >> 6;            // 4
    const int iS = (blk >> 3) & 7;      // 8
    const int jS = blk & 7;             // 8
    const int l15 = lane & 15;
    const int quad = lane >> 4;
    const int wi = wave & 3;            // i 16-band within the 64-row supertile
    const int wj = wave >> 2;           // j 32-half within the 64-col supertile

    // Stage j-rows o[b][jS*64 .. +63][0:256] into LDS (coalesced 16B copies).
    const unsigned short* jbase = o + (b * 512 + jS * 64) * 256;
    #pragma unroll
    for (int i = 0; i < 4; ++i) {
        const int idx = i * 512 + tid;      // 0..2047 = 64 rows x 32 chunks
        const int row = idx >> 5;
        const int c8  = idx & 31;
        *(bf16x8*)(&js[row * S2_LD + c8 * 8]) = *(const bf16x8*)(jbase + row * 256 + c8 * 8);
    }
    __syncthreads();

    const int ioff = ((b * 512 + iS * 64 + wi * 16 + l15) * 256) + quad * 8;
    const unsigned short* irow0 = u0 + ioff;
    const unsigned short* irow1 = u1 + ioff;

    f32x4 acc0[2], acc1[2];
    #pragma unroll
    for (int g = 0; g < 2; ++g) {
        acc0[g] = (f32x4){0.f, 0.f, 0.f, 0.f};
        acc1[g] = (f32x4){0.f, 0.f, 0.f, 0.f};
    }

    #pragma unroll
    for (int s = 0; s < 8; ++s) {
        const int k = s * 32;
        bf16x8 a0 = *(const bf16x8*)(irow0 + k);
        bf16x8 a1 = *(const bf16x8*)(irow1 + k);
        #pragma unroll
        for (int g = 0; g < 2; ++g) {
            bf16x8 bj = *(const bf16x8*)(&js[(wj * 32 + g * 16 + l15) * S2_LD + k + quad * 8]);
            acc0[g] = __builtin_amdgcn_mfma_f32_16x16x32_bf16(a0, bj, acc0[g], 0, 0, 0);
            acc1[g] = __builtin_amdgcn_mfma_f32_16x16x32_bf16(a1, bj, acc1[g], 0, 0, 0);
        }
    }

    const float bias0 = b2[0];
    const float bias1 = b2[1];
    #pragma unroll
    for (int g = 0; g < 2; ++g) {
        const int j = jS * 64 + wj * 32 + g * 16 + l15;      // n-index = lane&15
        #pragma unroll
        for (int r = 0; r < 4; ++r) {
            const int i = iS * 64 + wi * 16 + quad * 4 + r;  // m-index
            f32x2 v;
            v[0] = acc0[g][r] + bias0;
            v[1] = acc1[g][r] + bias1;
            *(f32x2*)(out + (((b * 512 + i) * 512) + j) * 2) = v;
        }
    }
}

extern "C" void kernel_launch(void* const* d_in, const int* in_sizes, int n_in,
                              void* d_out, int out_size, void* d_ws, size_t ws_size,
                              hipStream_t stream) {
    const float* x  = (const float*)d_in[0];   // [4,512,1024] fp32
    const float* W1 = (const float*)d_in[1];   // [256,1024] fp32
    const float* b1 = (const float*)d_in[2];   // [256] fp32
    const float* W2 = (const float*)d_in[3];   // [2,256] fp32
    const float* b2 = (const float*)d_in[4];   // [2] fp32
    float* out = (float*)d_out;                // [4,512,512,2] fp32

    // ws layout (256 MiB available):
    //   o  bf16 [2048][256] @ 0      (1 MB)
    //   u0 bf16 [2048][256] @ 1 MB   (1 MB)
    //   u1 bf16 [2048][256] @ 2 MB   (1 MB)
    //   P  bf16 [16][2048][256] @ 3 MB (16 MB)
    unsigned short* o  = (unsigned short*)d_ws;
    unsigned short* u0 = (unsigned short*)((char*)d_ws + (1u << 20));
    unsigned short* u1 = (unsigned short*)((char*)d_ws + (2u << 20));
    unsigned short* P  = (unsigned short*)((char*)d_ws + (3u << 20));

    s1_gemm      <<<1024, 256, 0, stream>>>(x, W1, P);
    s1_reduce    <<< 512, 256, 0, stream>>>(P, b1, W2, o, u0, u1);
    stage2_kernel<<< 256, 512, 0, stream>>>(o, u0, u1, b2, out);
}